// Round 13
// baseline (403.173 us; speedup 1.0000x reference)
//
#include <hip/hip_runtime.h>
#include <stdint.h>

// ---------------------------------------------------------------------------
// D-ETM decoder: alphas = mu + eps*exp(0.5*ls); KL; beta = softmax(alphas@W^T)
// out = [beta (125M f32), kl (1 f32)]
//
// R13: R12 (MX-fp8 recompute two-pass) +
//   - k1: 2048 grid-stride blocks (was 52.7K tiny blocks), float4 W reads
//   - K-loop: kt=1 tile prefetched to registers (T14) while kt=0 stages and
//     computes; ds_write rebuilds the identical swizzled LDS image, so acc
//     stays bit-identical between pass1 and pass2.
//   - pass2 Ms/Ss preload moved after the K-loop (keeps vmcnt(8) count exact)
//
// ws (~18 MB): Wp8[50176][256] u8 @0; Ap8[2560][256] u8 @12,845,056;
//   pm[196][2560] f32 @13,500,416; ps @15,507,456; bs @17,514,496;
//   Ms @17,524,736; Ss @17,534,976
// ---------------------------------------------------------------------------

typedef float f32x4 __attribute__((ext_vector_type(4)));
typedef int i32x8 __attribute__((ext_vector_type(8)));

#define TT 50
#define KTOP 50
#define RHO 256
#define VOCAB 50000
#define NROWS 2500
#define MPAD 2560
#define BM 256
#define BN 256
#define BK 128
#define NTN 196          // ceil(50000/256)
#define NTM 10           // 2560/256
#define NPADV (NTN * BN) // 50176
#define NVB_W 12544      // NPADV*256/1024 f32x4-chunks of W per 256-thr block
#define LOG_DELTA (-5.29831736f)

#define AS1(p) ((__attribute__((address_space(1))) void*)(uintptr_t)(p))
#define AS3(p) ((__attribute__((address_space(3))) void*)(p))

__device__ __forceinline__ uint8_t to_fp8(float x) {
    int pk = __builtin_amdgcn_cvt_pk_fp8_f32(x, 0.0f, 0, false);
    return (uint8_t)(pk & 0xFF);
}

// ---- K1: grid-stride: A rows + KL (vb<MPAD); W cast float4 (vb>=MPAD) -----
__global__ __launch_bounds__(256) void k1_prep(
    const float* __restrict__ mu, const float* __restrict__ ls,
    const float* __restrict__ eps, const float* __restrict__ W,
    uint8_t* __restrict__ Ap8, uint8_t* __restrict__ Wp8,
    float* __restrict__ blksum)
{
    __shared__ float sred[256];
    const int r = threadIdx.x;
    for (int vb = blockIdx.x; vb < MPAD + NVB_W; vb += gridDim.x) {
        if (vb >= MPAD) {
            // W chunk: 1024 elems per virtual block, 4 per thread
            long e0 = (long)(vb - MPAD) * 1024 + r * 4;
            long v = e0 >> 8;
            uchar4 o;
            if (v < VOCAB) {
                float4 w = *(const float4*)(W + e0);
                o.x = to_fp8(w.x); o.y = to_fp8(w.y);
                o.z = to_fp8(w.z); o.w = to_fp8(w.w);
            } else {
                o.x = o.y = o.z = o.w = 0;
            }
            *(uchar4*)(Wp8 + e0) = o;
            continue;
        }
        int b = vb;
        if (b >= NROWS) { Ap8[(long)b * RHO + r] = 0; continue; }
        int t = b / KTOP;
        int k = b - t * KTOP;
        long iMu = ((long)k * TT + t) * RHO + r;
        long iEp = ((long)t * KTOP + k) * RHO + r;
        float m = mu[iMu], l = ls[iMu], e = eps[iEp];
        float alpha = fmaf(e, __expf(0.5f * l), m);
        Ap8[(long)b * RHO + r] = to_fp8(alpha);

        float p_mu = 0.0f, p_ls = 0.0f, denom = 1.0f + 1e-6f;
        if (t > 0) {
            float m0 = mu[iMu - RHO];
            float l0 = ls[iMu - RHO];
            float e0 = eps[iEp - (long)KTOP * RHO];
            p_mu = fmaf(e0, __expf(0.5f * l0), m0);
            p_ls = LOG_DELTA;
            denom = 0.005f + 1e-6f;
        }
        float sq = __expf(l);
        float d = m - p_mu;
        float term = (sq + d * d) / denom - 1.0f + p_ls - l;

        sred[r] = term;
        __syncthreads();
        for (int s = 128; s > 0; s >>= 1) {
            if (r < s) sred[r] += sred[r + s];
            __syncthreads();
        }
        if (r == 0) blksum[b] = sred[0];
    }
}

// ---- shared fp8 GEMM machinery --------------------------------------------
// LDS rows are 128 B. Stage/prefetch place global 16B chunk (c ^ (row&7)) at
// physical chunk c; ds_read of logical 8B unit u uses physical u^((row&7)<<1).
#define GEMM_PRELUDE(EXTRA)                                                    \
    __shared__ alignas(16) char lds_raw[65536 + EXTRA];                        \
    uint8_t* As = (uint8_t*)lds_raw;                 /* [256][128] 32 KB */    \
    uint8_t* Ws = (uint8_t*)(lds_raw + 32768);       /* [256][128] 32 KB */    \
    const int tid = threadIdx.x;                                               \
    const int wave = tid >> 6;                                                 \
    const int lane = tid & 63;                                                 \
    const int bid = blockIdx.x;                                                \
    const int orig = (bid & 7) * 245 + (bid >> 3);   /* 1960 = 8*245 */        \
    const int tm = orig % NTM;                                                 \
    const int tn = orig / NTM;                                                 \
    const int wr = wave >> 2;    /* 0..1 : 128-row half   */                   \
    const int wc = wave & 3;     /* 0..3 : 64-col quarter */                   \
    const int lhi = lane >> 4;                                                 \
    const int llo = lane & 15;                                                 \
    f32x4 acc[8][4];                                                           \
    _Pragma("unroll")                                                          \
    for (int m = 0; m < 8; ++m)                                                \
        _Pragma("unroll")                                                      \
        for (int n = 0; n < 4; ++n)                                            \
            _Pragma("unroll")                                                  \
            for (int i = 0; i < 4; ++i) acc[m][n][i] = 0.0f;                   \
    const long arow0 = (long)tm * BM;                                          \
    const long wrow0 = (long)tn * BN;

// Fragment: lane covers k = lhi*32..+31 = logical 8B units lhi*4+p, p=0..3
#define LOADFRAG(dst, BASE, r)                                                 \
    {                                                                          \
        union { long l[4]; i32x8 v; } u_;                                      \
        _Pragma("unroll")                                                      \
        for (int p = 0; p < 4; ++p) {                                          \
            int unit = (lhi * 4 + p) ^ (((r) & 7) << 1);                       \
            u_.l[p] = *(const long*)&BASE[(r) * BK + (unit << 3)];             \
        }                                                                      \
        dst = u_.v;                                                            \
    }

#define COMPUTE                                                                \
    {                                                                          \
        i32x8 bfr[4];                                                          \
        _Pragma("unroll")                                                      \
        for (int n = 0; n < 4; ++n) {                                          \
            int r = wc * 64 + n * 16 + llo;                                    \
            LOADFRAG(bfr[n], Ws, r)                                            \
        }                                                                      \
        _Pragma("unroll")                                                      \
        for (int h = 0; h < 2; ++h) {                                          \
            i32x8 af[4];                                                       \
            _Pragma("unroll")                                                  \
            for (int mm = 0; mm < 4; ++mm) {                                   \
                int r = wr * 128 + (h * 4 + mm) * 16 + llo;                    \
                LOADFRAG(af[mm], As, r)                                        \
            }                                                                  \
            _Pragma("unroll")                                                  \
            for (int mm = 0; mm < 4; ++mm)                                     \
                _Pragma("unroll")                                              \
                for (int n = 0; n < 4; ++n)                                    \
                    acc[h * 4 + mm][n] =                                       \
                        __builtin_amdgcn_mfma_scale_f32_16x16x128_f8f6f4(      \
                            af[mm], bfr[n], acc[h * 4 + mm][n],                \
                            0, 0, 0, 0x7F7F7F7F, 0, 0x7F7F7F7F);               \
        }                                                                      \
    }

// K-loop with kt=1 register-prefetch (T14). LDS image identical to a staged
// load, so pass1/pass2 stay bit-identical.
#define KLOOP                                                                  \
    uint4 pfA[4], pfW[4];                                                      \
    {   /* stage kt=0 via global_load_lds (8 vm ops/wave) */                   \
        _Pragma("unroll")                                                      \
        for (int j = 0; j < 4; ++j) {                                          \
            int row = j * 64 + (tid >> 3);                                     \
            int c   = tid & 7;                                                 \
            int gc  = (c ^ (row & 7)) * 16;                                    \
            const uint8_t* sA = Ap8 + (arow0 + row) * RHO + gc;                \
            __builtin_amdgcn_global_load_lds(AS1(sA),                          \
                AS3(As + row * BK + c * 16), 16, 0, 0);                        \
            const uint8_t* sW = Wp8 + (wrow0 + row) * RHO + gc;                \
            __builtin_amdgcn_global_load_lds(AS1(sW),                          \
                AS3(Ws + row * BK + c * 16), 16, 0, 0);                        \
        }                                                                      \
    }                                                                          \
    __builtin_amdgcn_sched_barrier(0);                                         \
    {   /* prefetch kt=1 to regs (8 vm ops/wave) */                            \
        _Pragma("unroll")                                                      \
        for (int j = 0; j < 4; ++j) {                                          \
            int row = j * 64 + (tid >> 3);                                     \
            int c   = tid & 7;                                                 \
            int gc  = (c ^ (row & 7)) * 16;                                    \
            pfA[j] = *(const uint4*)(Ap8 + (arow0 + row) * RHO + BK + gc);     \
            pfW[j] = *(const uint4*)(Wp8 + (wrow0 + row) * RHO + BK + gc);     \
        }                                                                      \
    }                                                                          \
    __builtin_amdgcn_sched_barrier(0);                                         \
    asm volatile("s_waitcnt vmcnt(8)\n\ts_barrier" ::: "memory");              \
    __builtin_amdgcn_sched_barrier(0);                                         \
    COMPUTE                                                                    \
    __syncthreads();                                                           \
    {   /* rebuild kt=1 LDS image from regs */                                 \
        _Pragma("unroll")                                                      \
        for (int j = 0; j < 4; ++j) {                                          \
            int row = j * 64 + (tid >> 3);                                     \
            int c   = tid & 7;                                                 \
            *(uint4*)(As + row * BK + c * 16) = pfA[j];                        \
            *(uint4*)(Ws + row * BK + c * 16) = pfW[j];                        \
        }                                                                      \
    }                                                                          \
    __syncthreads();                                                           \
    COMPUTE

// ---- K2 pass 1: fp8 GEMM -> per-tile (max, sumexp) partials ---------------
__global__ __launch_bounds__(512, 2) void k2_pass1(
    const uint8_t* __restrict__ Ap8, const uint8_t* __restrict__ Wp8,
    float* __restrict__ pm, float* __restrict__ ps)
{
    GEMM_PRELUDE(8192)
    float* red_m = (float*)(lds_raw + 65536);        // [4][256]
    float* red_s = (float*)(lds_raw + 69632);        // [4][256]
    KLOOP
    __syncthreads();

#pragma unroll
    for (int m = 0; m < 8; ++m) {
#pragma unroll
        for (int i = 0; i < 4; ++i) {
            float mx = -1e30f;
#pragma unroll
            for (int n = 0; n < 4; ++n) {
                int cg = tn * BN + wc * 64 + n * 16 + llo;
                if (cg < VOCAB) mx = fmaxf(mx, acc[m][n][i]);
            }
#pragma unroll
            for (int dm = 1; dm < 16; dm <<= 1) mx = fmaxf(mx, __shfl_xor(mx, dm));
            float sm = 0.0f;
#pragma unroll
            for (int n = 0; n < 4; ++n) {
                int cg = tn * BN + wc * 64 + n * 16 + llo;
                if (cg < VOCAB) sm += __expf(acc[m][n][i] - mx);
            }
#pragma unroll
            for (int dm = 1; dm < 16; dm <<= 1) sm += __shfl_xor(sm, dm);
            if (llo == 0) {
                int rl = wr * 128 + m * 16 + lhi * 4 + i;   // 0..255
                red_m[wc * 256 + rl] = mx;
                red_s[wc * 256 + rl] = sm;
            }
        }
    }
    __syncthreads();
    if (tid < BM) {
        float M = red_m[tid];
#pragma unroll
        for (int w = 1; w < 4; ++w) M = fmaxf(M, red_m[w * 256 + tid]);
        float S = 0.0f;
#pragma unroll
        for (int w = 0; w < 4; ++w) S += red_s[w * 256 + tid] * __expf(red_m[w * 256 + tid] - M);
        long idx = (long)tn * MPAD + tm * BM + tid;
        pm[idx] = M;
        ps[idx] = S;
    }
}

// ---- K3: per-row (M,S) from partials (blocks 0..9); kl reduce (block 10) --
__global__ __launch_bounds__(256) void k3_stats(
    const float* __restrict__ pm, const float* __restrict__ ps,
    const float* __restrict__ blksum,
    float* __restrict__ Ms, float* __restrict__ Ss, float* __restrict__ kl_out)
{
    if (blockIdx.x == 10) {
        __shared__ float sred[256];
        float s = 0.0f;
        for (int i = threadIdx.x; i < NROWS; i += 256) s += blksum[i];
        sred[threadIdx.x] = s;
        __syncthreads();
        for (int st = 128; st > 0; st >>= 1) {
            if (threadIdx.x < st) sred[threadIdx.x] += sred[threadIdx.x + st];
            __syncthreads();
        }
        if (threadIdx.x == 0) kl_out[0] = 0.5f * sred[0];
        return;
    }
    int row = blockIdx.x * 256 + threadIdx.x;
    if (row >= NROWS) return;
    float M = -1e30f;
    for (int j = 0; j < NTN; ++j) M = fmaxf(M, pm[(long)j * MPAD + row]);
    float S = 0.0f;
    for (int j = 0; j < NTN; ++j)
        S += ps[(long)j * MPAD + row] * __expf(pm[(long)j * MPAD + row] - M);
    Ms[row] = M;
    Ss[row] = S;
}

// ---- K2 pass 2: identical fp8 GEMM -> beta = exp(acc - M)/S -> d_out ------
__global__ __launch_bounds__(512, 2) void k2_pass2(
    const uint8_t* __restrict__ Ap8, const uint8_t* __restrict__ Wp8,
    const float* __restrict__ Ms, const float* __restrict__ Ss,
    float* __restrict__ out)
{
    GEMM_PRELUDE(2048)
    float* ms_lds = (float*)(lds_raw + 65536);       // [256]
    float* ss_lds = (float*)(lds_raw + 66560);       // [256] (1/S)
    KLOOP
    // load row stats AFTER the K-loop (keeps the vmcnt(8) count exact)
    if (tid < BM) {
        long rg = arow0 + tid;
        float Mv = 0.0f, Sv = 1.0f;
        if (rg < NROWS) { Mv = Ms[rg]; Sv = Ss[rg]; }
        ms_lds[tid] = Mv;
        ss_lds[tid] = 1.0f / Sv;
    }
    __syncthreads();

#pragma unroll
    for (int m = 0; m < 8; ++m) {
#pragma unroll
        for (int i = 0; i < 4; ++i) {
            int rl = wr * 128 + m * 16 + lhi * 4 + i;
            long rg = arow0 + rl;
            if (rg < NROWS) {
                float M = ms_lds[rl];
                float invS = ss_lds[rl];
                float* orow = out + rg * (long)VOCAB;
#pragma unroll
                for (int n = 0; n < 4; ++n) {
                    int cg = tn * BN + wc * 64 + n * 16 + llo;
                    if (cg < VOCAB) orow[cg] = __expf(acc[m][n][i] - M) * invS;
                }
            }
        }
    }
}

extern "C" void kernel_launch(void* const* d_in, const int* in_sizes, int n_in,
                              void* d_out, int out_size, void* d_ws, size_t ws_size,
                              hipStream_t stream) {
    const float* mu  = (const float*)d_in[0];
    const float* ls  = (const float*)d_in[1];
    const float* eps = (const float*)d_in[2];
    const float* W   = (const float*)d_in[3];
    char* ws = (char*)d_ws;

    uint8_t* Wp8 = (uint8_t*)(ws);
    uint8_t* Ap8 = (uint8_t*)(ws + 12845056L);
    float* pm  = (float*)(ws + 13500416L);
    float* ps  = (float*)(ws + 15507456L);
    float* bs  = (float*)(ws + 17514496L);
    float* Ms  = (float*)(ws + 17524736L);
    float* Ss  = (float*)(ws + 17534976L);
    float* kl  = (float*)d_out + 125000000L;

    k1_prep<<<2048, 256, 0, stream>>>(mu, ls, eps, W, Ap8, Wp8, bs);
    k2_pass1<<<NTM * NTN, 512, 0, stream>>>(Ap8, Wp8, pm, ps);
    k3_stats<<<11, 256, 0, stream>>>(pm, ps, bs, Ms, Ss, kl);
    k2_pass2<<<NTM * NTN, 512, 0, stream>>>(Ap8, Wp8, Ms, Ss, (float*)d_out);
}

// Round 14
// 339.686 us; speedup vs baseline: 1.1869x; 1.1869x over previous
//
#include <hip/hip_runtime.h>
#include <stdint.h>

// ---------------------------------------------------------------------------
// D-ETM decoder: alphas = mu + eps*exp(0.5*ls); KL; beta = softmax(alphas@W^T)
// out = [beta (125M f32), kl (1 f32)]
//
// R14: R12 (MX-fp8 recompute two-pass) +
//   - k1: 2048 grid-stride blocks, float4 W reads (from R13 — kept)
//   - K-loop: LDS double-buffer with counted vmcnt (VGPR-neutral overlap;
//     R13's reg-prefetch cost 32 VGPR at the 256-reg occupancy cliff and
//     regressed +48 us — reverted). Both K-tiles' global_load_lds issued
//     up front; vmcnt(8) gates kt0 compute, vmcnt(0) gates kt1.
//   LDS: 4 x 32 KB buffers + reductions = 136 KB (pass1) / 130 KB (pass2);
//   occupancy already VGPR-capped at 1 block/CU so dbuf is free.
//
// ws (~18 MB): Wp8[50176][256] u8 @0; Ap8[2560][256] u8 @12,845,056;
//   pm[196][2560] f32 @13,500,416; ps @15,507,456; bs @17,514,496;
//   Ms @17,524,736; Ss @17,534,976
// ---------------------------------------------------------------------------

typedef float f32x4 __attribute__((ext_vector_type(4)));
typedef int i32x8 __attribute__((ext_vector_type(8)));

#define TT 50
#define KTOP 50
#define RHO 256
#define VOCAB 50000
#define NROWS 2500
#define MPAD 2560
#define BM 256
#define BN 256
#define BK 128
#define NTN 196          // ceil(50000/256)
#define NTM 10           // 2560/256
#define NPADV (NTN * BN) // 50176
#define NVB_W 12544      // NPADV*256/1024 chunks of W per 256-thr block
#define LOG_DELTA (-5.29831736f)

#define AS1(p) ((__attribute__((address_space(1))) void*)(uintptr_t)(p))
#define AS3(p) ((__attribute__((address_space(3))) void*)(p))

__device__ __forceinline__ uint8_t to_fp8(float x) {
    int pk = __builtin_amdgcn_cvt_pk_fp8_f32(x, 0.0f, 0, false);
    return (uint8_t)(pk & 0xFF);
}

// ---- K1: grid-stride: A rows + KL (vb<MPAD); W cast float4 (vb>=MPAD) -----
__global__ __launch_bounds__(256) void k1_prep(
    const float* __restrict__ mu, const float* __restrict__ ls,
    const float* __restrict__ eps, const float* __restrict__ W,
    uint8_t* __restrict__ Ap8, uint8_t* __restrict__ Wp8,
    float* __restrict__ blksum)
{
    __shared__ float sred[256];
    const int r = threadIdx.x;
    for (int vb = blockIdx.x; vb < MPAD + NVB_W; vb += gridDim.x) {
        if (vb >= MPAD) {
            long e0 = (long)(vb - MPAD) * 1024 + r * 4;
            long v = e0 >> 8;
            uchar4 o;
            if (v < VOCAB) {
                float4 w = *(const float4*)(W + e0);
                o.x = to_fp8(w.x); o.y = to_fp8(w.y);
                o.z = to_fp8(w.z); o.w = to_fp8(w.w);
            } else {
                o.x = o.y = o.z = o.w = 0;
            }
            *(uchar4*)(Wp8 + e0) = o;
            continue;
        }
        int b = vb;
        if (b >= NROWS) { Ap8[(long)b * RHO + r] = 0; continue; }
        int t = b / KTOP;
        int k = b - t * KTOP;
        long iMu = ((long)k * TT + t) * RHO + r;
        long iEp = ((long)t * KTOP + k) * RHO + r;
        float m = mu[iMu], l = ls[iMu], e = eps[iEp];
        float alpha = fmaf(e, __expf(0.5f * l), m);
        Ap8[(long)b * RHO + r] = to_fp8(alpha);

        float p_mu = 0.0f, p_ls = 0.0f, denom = 1.0f + 1e-6f;
        if (t > 0) {
            float m0 = mu[iMu - RHO];
            float l0 = ls[iMu - RHO];
            float e0 = eps[iEp - (long)KTOP * RHO];
            p_mu = fmaf(e0, __expf(0.5f * l0), m0);
            p_ls = LOG_DELTA;
            denom = 0.005f + 1e-6f;
        }
        float sq = __expf(l);
        float d = m - p_mu;
        float term = (sq + d * d) / denom - 1.0f + p_ls - l;

        sred[r] = term;
        __syncthreads();
        for (int s = 128; s > 0; s >>= 1) {
            if (r < s) sred[r] += sred[r + s];
            __syncthreads();
        }
        if (r == 0) blksum[b] = sred[0];
        __syncthreads();
    }
}

// ---- shared fp8 GEMM machinery --------------------------------------------
// LDS rows are 128 B. Stage places global 16B chunk (c ^ (row&7)) at
// physical chunk c; ds_read of logical 8B unit u uses physical u^((row&7)<<1).
#define GEMM_PRELUDE(EXTRA)                                                    \
    __shared__ alignas(16) char lds_raw[131072 + EXTRA];                       \
    uint8_t* As0 = (uint8_t*)lds_raw;                /* [256][128] 32 KB */    \
    uint8_t* Ws0 = (uint8_t*)(lds_raw + 32768);                                \
    uint8_t* As1 = (uint8_t*)(lds_raw + 65536);                                \
    uint8_t* Ws1 = (uint8_t*)(lds_raw + 98304);                                \
    const int tid = threadIdx.x;                                               \
    const int wave = tid >> 6;                                                 \
    const int lane = tid & 63;                                                 \
    const int bid = blockIdx.x;                                                \
    const int orig = (bid & 7) * 245 + (bid >> 3);   /* 1960 = 8*245 */        \
    const int tm = orig % NTM;                                                 \
    const int tn = orig / NTM;                                                 \
    const int wr = wave >> 2;    /* 0..1 : 128-row half   */                   \
    const int wc = wave & 3;     /* 0..3 : 64-col quarter */                   \
    const int lhi = lane >> 4;                                                 \
    const int llo = lane & 15;                                                 \
    f32x4 acc[8][4];                                                           \
    _Pragma("unroll")                                                          \
    for (int m = 0; m < 8; ++m)                                                \
        _Pragma("unroll")                                                      \
        for (int n = 0; n < 4; ++n)                                            \
            _Pragma("unroll")                                                  \
            for (int i = 0; i < 4; ++i) acc[m][n][i] = 0.0f;                   \
    const long arow0 = (long)tm * BM;                                          \
    const long wrow0 = (long)tn * BN;

#define STAGE(AB, WB, kt)                                                      \
    {                                                                          \
        _Pragma("unroll")                                                      \
        for (int j = 0; j < 4; ++j) {                                          \
            int row = j * 64 + (tid >> 3);           /* 0..255 */              \
            int c   = tid & 7;                       /* 16B chunk */           \
            int gc  = (c ^ (row & 7)) * 16;                                    \
            const uint8_t* sA = Ap8 + (arow0 + row) * RHO + (kt) * BK + gc;    \
            __builtin_amdgcn_global_load_lds(AS1(sA),                          \
                AS3(AB + row * BK + c * 16), 16, 0, 0);                        \
            const uint8_t* sW = Wp8 + (wrow0 + row) * RHO + (kt) * BK + gc;    \
            __builtin_amdgcn_global_load_lds(AS1(sW),                          \
                AS3(WB + row * BK + c * 16), 16, 0, 0);                        \
        }                                                                      \
    }

// Fragment: lane covers k = lhi*32..+31 = logical 8B units lhi*4+p, p=0..3
#define LOADFRAG(dst, BASE, r)                                                 \
    {                                                                          \
        union { long l[4]; i32x8 v; } u_;                                      \
        _Pragma("unroll")                                                      \
        for (int p = 0; p < 4; ++p) {                                          \
            int unit = (lhi * 4 + p) ^ (((r) & 7) << 1);                       \
            u_.l[p] = *(const long*)&BASE[(r) * BK + (unit << 3)];             \
        }                                                                      \
        dst = u_.v;                                                            \
    }

#define COMPUTE(AB, WB)                                                        \
    {                                                                          \
        i32x8 bfr[4];                                                          \
        _Pragma("unroll")                                                      \
        for (int n = 0; n < 4; ++n) {                                          \
            int r = wc * 64 + n * 16 + llo;                                    \
            LOADFRAG(bfr[n], WB, r)                                            \
        }                                                                      \
        _Pragma("unroll")                                                      \
        for (int h = 0; h < 2; ++h) {                                          \
            i32x8 af[4];                                                       \
            _Pragma("unroll")                                                  \
            for (int mm = 0; mm < 4; ++mm) {                                   \
                int r = wr * 128 + (h * 4 + mm) * 16 + llo;                    \
                LOADFRAG(af[mm], AB, r)                                        \
            }                                                                  \
            _Pragma("unroll")                                                  \
            for (int mm = 0; mm < 4; ++mm)                                     \
                _Pragma("unroll")                                              \
                for (int n = 0; n < 4; ++n)                                    \
                    acc[h * 4 + mm][n] =                                       \
                        __builtin_amdgcn_mfma_scale_f32_16x16x128_f8f6f4(      \
                            af[mm], bfr[n], acc[h * 4 + mm][n],                \
                            0, 0, 0, 0x7F7F7F7F, 0, 0x7F7F7F7F);               \
        }                                                                      \
    }

// Double-buffered K-loop with counted vmcnt: both K-tiles issued up front
// (16 vm ops/wave); vmcnt(8) gates kt0, vmcnt(0) gates kt1.
#define KLOOP                                                                  \
    STAGE(As0, Ws0, 0)                                                         \
    STAGE(As1, Ws1, 1)                                                         \
    asm volatile("s_waitcnt vmcnt(8)\n\ts_barrier" ::: "memory");              \
    __builtin_amdgcn_sched_barrier(0);                                         \
    COMPUTE(As0, Ws0)                                                          \
    asm volatile("s_waitcnt vmcnt(0)\n\ts_barrier" ::: "memory");              \
    __builtin_amdgcn_sched_barrier(0);                                         \
    COMPUTE(As1, Ws1)

// ---- K2 pass 1: fp8 GEMM -> per-tile (max, sumexp) partials ---------------
__global__ __launch_bounds__(512, 2) void k2_pass1(
    const uint8_t* __restrict__ Ap8, const uint8_t* __restrict__ Wp8,
    float* __restrict__ pm, float* __restrict__ ps)
{
    GEMM_PRELUDE(8192)
    float* red_m = (float*)(lds_raw + 131072);       // [4][256]
    float* red_s = (float*)(lds_raw + 135168);       // [4][256]
    KLOOP

#pragma unroll
    for (int m = 0; m < 8; ++m) {
#pragma unroll
        for (int i = 0; i < 4; ++i) {
            float mx = -1e30f;
#pragma unroll
            for (int n = 0; n < 4; ++n) {
                int cg = tn * BN + wc * 64 + n * 16 + llo;
                if (cg < VOCAB) mx = fmaxf(mx, acc[m][n][i]);
            }
#pragma unroll
            for (int dm = 1; dm < 16; dm <<= 1) mx = fmaxf(mx, __shfl_xor(mx, dm));
            float sm = 0.0f;
#pragma unroll
            for (int n = 0; n < 4; ++n) {
                int cg = tn * BN + wc * 64 + n * 16 + llo;
                if (cg < VOCAB) sm += __expf(acc[m][n][i] - mx);
            }
#pragma unroll
            for (int dm = 1; dm < 16; dm <<= 1) sm += __shfl_xor(sm, dm);
            if (llo == 0) {
                int rl = wr * 128 + m * 16 + lhi * 4 + i;   // 0..255
                red_m[wc * 256 + rl] = mx;
                red_s[wc * 256 + rl] = sm;
            }
        }
    }
    __syncthreads();
    if (tid < BM) {
        float M = red_m[tid];
#pragma unroll
        for (int w = 1; w < 4; ++w) M = fmaxf(M, red_m[w * 256 + tid]);
        float S = 0.0f;
#pragma unroll
        for (int w = 0; w < 4; ++w) S += red_s[w * 256 + tid] * __expf(red_m[w * 256 + tid] - M);
        long idx = (long)tn * MPAD + tm * BM + tid;
        pm[idx] = M;
        ps[idx] = S;
    }
}

// ---- K3: per-row (M,S) from partials (blocks 0..9); kl reduce (block 10) --
__global__ __launch_bounds__(256) void k3_stats(
    const float* __restrict__ pm, const float* __restrict__ ps,
    const float* __restrict__ blksum,
    float* __restrict__ Ms, float* __restrict__ Ss, float* __restrict__ kl_out)
{
    if (blockIdx.x == 10) {
        __shared__ float sred[256];
        float s = 0.0f;
        for (int i = threadIdx.x; i < NROWS; i += 256) s += blksum[i];
        sred[threadIdx.x] = s;
        __syncthreads();
        for (int st = 128; st > 0; st >>= 1) {
            if (threadIdx.x < st) sred[threadIdx.x] += sred[threadIdx.x + st];
            __syncthreads();
        }
        if (threadIdx.x == 0) kl_out[0] = 0.5f * sred[0];
        return;
    }
    int row = blockIdx.x * 256 + threadIdx.x;
    if (row >= NROWS) return;
    float M = -1e30f;
    for (int j = 0; j < NTN; ++j) M = fmaxf(M, pm[(long)j * MPAD + row]);
    float S = 0.0f;
    for (int j = 0; j < NTN; ++j)
        S += ps[(long)j * MPAD + row] * __expf(pm[(long)j * MPAD + row] - M);
    Ms[row] = M;
    Ss[row] = S;
}

// ---- K2 pass 2: identical fp8 GEMM -> beta = exp(acc - M)/S -> d_out ------
__global__ __launch_bounds__(512, 2) void k2_pass2(
    const uint8_t* __restrict__ Ap8, const uint8_t* __restrict__ Wp8,
    const float* __restrict__ Ms, const float* __restrict__ Ss,
    float* __restrict__ out)
{
    GEMM_PRELUDE(2048)
    float* ms_lds = (float*)(lds_raw + 131072);      // [256]
    float* ss_lds = (float*)(lds_raw + 132096);      // [256] (1/S)
    KLOOP
    // load row stats AFTER the K-loop (keeps the vmcnt counts exact)
    if (tid < BM) {
        long rg = arow0 + tid;
        float Mv = 0.0f, Sv = 1.0f;
        if (rg < NROWS) { Mv = Ms[rg]; Sv = Ss[rg]; }
        ms_lds[tid] = Mv;
        ss_lds[tid] = 1.0f / Sv;
    }
    __syncthreads();

#pragma unroll
    for (int m = 0; m < 8; ++m) {
#pragma unroll
        for (int i = 0; i < 4; ++i) {
            int rl = wr * 128 + m * 16 + lhi * 4 + i;
            long rg = arow0 + rl;
            if (rg < NROWS) {
                float M = ms_lds[rl];
                float invS = ss_lds[rl];
                float* orow = out + rg * (long)VOCAB;
#pragma unroll
                for (int n = 0; n < 4; ++n) {
                    int cg = tn * BN + wc * 64 + n * 16 + llo;
                    if (cg < VOCAB) orow[cg] = __expf(acc[m][n][i] - M) * invS;
                }
            }
        }
    }
}

extern "C" void kernel_launch(void* const* d_in, const int* in_sizes, int n_in,
                              void* d_out, int out_size, void* d_ws, size_t ws_size,
                              hipStream_t stream) {
    const float* mu  = (const float*)d_in[0];
    const float* ls  = (const float*)d_in[1];
    const float* eps = (const float*)d_in[2];
    const float* W   = (const float*)d_in[3];
    char* ws = (char*)d_ws;

    uint8_t* Wp8 = (uint8_t*)(ws);
    uint8_t* Ap8 = (uint8_t*)(ws + 12845056L);
    float* pm  = (float*)(ws + 13500416L);
    float* ps  = (float*)(ws + 15507456L);
    float* bs  = (float*)(ws + 17514496L);
    float* Ms  = (float*)(ws + 17524736L);
    float* Ss  = (float*)(ws + 17534976L);
    float* kl  = (float*)d_out + 125000000L;

    k1_prep<<<2048, 256, 0, stream>>>(mu, ls, eps, W, Ap8, Wp8, bs);
    k2_pass1<<<NTM * NTN, 512, 0, stream>>>(Ap8, Wp8, pm, ps);
    k3_stats<<<11, 256, 0, stream>>>(pm, ps, bs, Ms, Ss, kl);
    k2_pass2<<<NTM * NTN, 512, 0, stream>>>(Ap8, Wp8, Ms, Ss, (float*)d_out);
}